// Round 9
// baseline (1392.524 us; speedup 1.0000x reference)
//
#include <hip/hip_runtime.h>
#include <math.h>
#include <stdint.h>

#define B_ 128
#define T_ 1024
#define H_ 256
#define Z_ 64
#define M_ (B_ * T_)   // 131072 rows

typedef float     f4   __attribute__((ext_vector_type(4)));
typedef _Float16  h4_t __attribute__((ext_vector_type(4)));

// ---------------------------------------------------------------------------
// Kernel 1: precompute the non-recurrent part of both matmuls (unchanged).
// ---------------------------------------------------------------------------
__global__ __launch_bounds__(256) void precompute_kernel(
    const float* __restrict__ Hm,    // [M_, 256]
    const float* __restrict__ Wmu,   // [64, 320]
    const float* __restrict__ Wstd,  // [64, 320]
    const float* __restrict__ bmu,   // [64]
    const float* __restrict__ bstd,  // [64]
    float* __restrict__ pre_mu,      // [M_, 64]
    float* __restrict__ pre_std)     // [M_, 64]
{
    const int tid = threadIdx.x;
    const int ty = tid >> 4;
    const int tx = tid & 15;
    const int m0 = blockIdx.x * 64;

    __shared__ float Ash[64][17];
    __shared__ float Wm[64][17];
    __shared__ float Ws[64][17];

    float accm[4][4] = {};
    float accs[4][4] = {};

    const int lrow = tid >> 2;
    const int lk   = (tid & 3) * 4;

    for (int k0 = 0; k0 < 256; k0 += 16) {
        float4 av  = *reinterpret_cast<const float4*>(&Hm[(size_t)(m0 + lrow) * H_ + k0 + lk]);
        float4 wmv = *reinterpret_cast<const float4*>(&Wmu[(size_t)lrow * 320 + k0 + lk]);
        float4 wsv = *reinterpret_cast<const float4*>(&Wstd[(size_t)lrow * 320 + k0 + lk]);
        __syncthreads();
        Ash[lrow][lk + 0] = av.x;  Ash[lrow][lk + 1] = av.y;
        Ash[lrow][lk + 2] = av.z;  Ash[lrow][lk + 3] = av.w;
        Wm[lrow][lk + 0] = wmv.x;  Wm[lrow][lk + 1] = wmv.y;
        Wm[lrow][lk + 2] = wmv.z;  Wm[lrow][lk + 3] = wmv.w;
        Ws[lrow][lk + 0] = wsv.x;  Ws[lrow][lk + 1] = wsv.y;
        Ws[lrow][lk + 2] = wsv.z;  Ws[lrow][lk + 3] = wsv.w;
        __syncthreads();

        #pragma unroll
        for (int kk = 0; kk < 16; ++kk) {
            float a4[4], wm4[4], ws4[4];
            #pragma unroll
            for (int i = 0; i < 4; ++i) a4[i] = Ash[ty * 4 + i][kk];
            #pragma unroll
            for (int jj = 0; jj < 4; ++jj) wm4[jj] = Wm[tx * 4 + jj][kk];
            #pragma unroll
            for (int jj = 0; jj < 4; ++jj) ws4[jj] = Ws[tx * 4 + jj][kk];
            #pragma unroll
            for (int i = 0; i < 4; ++i)
                #pragma unroll
                for (int jj = 0; jj < 4; ++jj) {
                    accm[i][jj] += a4[i] * wm4[jj];
                    accs[i][jj] += a4[i] * ws4[jj];
                }
        }
    }

    float4 bm = *reinterpret_cast<const float4*>(&bmu[tx * 4]);
    float4 bs = *reinterpret_cast<const float4*>(&bstd[tx * 4]);
    #pragma unroll
    for (int i = 0; i < 4; ++i) {
        const size_t m = (size_t)(m0 + ty * 4 + i);
        float4 om, os;
        om.x = accm[i][0] + bm.x;  om.y = accm[i][1] + bm.y;
        om.z = accm[i][2] + bm.z;  om.w = accm[i][3] + bm.w;
        os.x = accs[i][0] + bs.x;  os.y = accs[i][1] + bs.y;
        os.z = accs[i][2] + bs.z;  os.w = accs[i][3] + bs.w;
        *reinterpret_cast<float4*>(&pre_mu[m * Z_ + tx * 4])  = om;
        *reinterpret_cast<float4*>(&pre_std[m * Z_ + tx * 4]) = os;
    }
}

// ---------------------------------------------------------------------------
// async 16B global -> LDS (wave-uniform LDS base; HW writes base + lane*16)
// ---------------------------------------------------------------------------
__device__ __forceinline__ void stage16(const float* g, float* lds_base) {
    __builtin_amdgcn_global_load_lds(
        (const __attribute__((address_space(1))) uint32_t*)(uintptr_t)g,
        (__attribute__((address_space(3))) uint32_t*)(uintptr_t)lds_base,
        16, 0, 0);
}

// ---------------------------------------------------------------------------
// Kernel 2: MFMA recurrence. One wave per 16 batch rows (8 blocks total).
//
// Layout identity (16x16x16 f16):
//   A: lane l holds A[m=l&15][k=4*(l>>4)+i]      (weights, 32 frags, 64 VGPRs)
//   B: lane l holds B[k=4*(l>>4)+i][n=l&15]      (z of prev step)
//   D: lane l holds D[m=4*(l>>4)+i][n=l&15]
// D's (m,lane) mapping == B's (k,lane) mapping, so step t's z output becomes
// step t+1's B operand with only f32->f16 converts — the 64-way z broadcast
// that cost readlanes/LDS round-trips in R2-R7 is done by the MFMA crossbar.
//
// pre_mu/pre_std/eps stream through LDS (depth-3 ring) via global_load_lds:
// no prefetch VGPRs (R4-R7 lesson: allocator caps us ~132). Counted
// s_waitcnt vmcnt(24) — NEVER vmcnt(0): stores stay in flight (R1 lesson).
// Invariant: buf for step t was staged >= 48 vmem ops ago, so vmcnt(24)
// always retires it without draining recent stores.
// ---------------------------------------------------------------------------
__global__ __launch_bounds__(64)
__attribute__((amdgpu_waves_per_eu(1, 1)))
void recurrent_kernel(
    const float* __restrict__ pre_mu,   // [M_, 64]
    const float* __restrict__ pre_std,  // [M_, 64]
    const float* __restrict__ eps,      // [B_, T_, 64]
    const float* __restrict__ Wmu,      // [64, 320]
    const float* __restrict__ Wstd,     // [64, 320]
    float* __restrict__ out)            // z | mu | std, each [B_, T_, 64]
{
    const int l   = threadIdx.x;
    const int col = l & 15;            // batch row within the 16-group
    const int g   = l >> 4;            // 0..3
    const int b0  = blockIdx.x * 16;

    // ---- A-fragments for both weight matrices: wm/ws[rt][kt], f16 ----
    h4_t wm[4][4], ws[4][4];
    #pragma unroll
    for (int rt = 0; rt < 4; ++rt) {
        #pragma unroll
        for (int kt = 0; kt < 4; ++kt) {
            const size_t off = (size_t)(rt * 16 + col) * 320 + 256 + kt * 16 + 4 * g;
            const f4 a = *reinterpret_cast<const f4*>(&Wmu[off]);
            const f4 s = *reinterpret_cast<const f4*>(&Wstd[off]);
            h4_t wa, wb;
            wa[0] = (_Float16)a[0]; wa[1] = (_Float16)a[1];
            wa[2] = (_Float16)a[2]; wa[3] = (_Float16)a[3];
            wb[0] = (_Float16)s[0]; wb[1] = (_Float16)s[1];
            wb[2] = (_Float16)s[2]; wb[3] = (_Float16)s[3];
            wm[rt][kt] = wa;
            ws[rt][kt] = wb;
        }
    }
    #pragma unroll
    for (int rt = 0; rt < 4; ++rt)
        #pragma unroll
        for (int kt = 0; kt < 4; ++kt) {
            asm volatile("" : "+v"(wm[rt][kt]));
            asm volatile("" : "+v"(ws[rt][kt]));
        }

    // LDS staging ring: 3 bufs x (4 pre_mu + 4 pre_std + 4 eps tiles) x 1KB
    __shared__ float stg[3][12][256];

    float* __restrict__ zo  = out;
    float* __restrict__ muo = out + (size_t)M_ * Z_;
    float* __restrict__ sdo = out + (size_t)2 * M_ * Z_;

    // prologue: stage t = 0, 1, 2
    #pragma unroll
    for (int s = 0; s < 3; ++s) {
        const size_t row = ((size_t)(b0 + col) * T_ + s) * 64 + 4 * g;
        #pragma unroll
        for (int rt = 0; rt < 4; ++rt) {
            stage16(pre_mu  + row + rt * 16, &stg[s][rt][0]);
            stage16(pre_std + row + rt * 16, &stg[s][4 + rt][0]);
            stage16(eps     + row + rt * 16, &stg[s][8 + rt][0]);
        }
    }

    // z_{-1} = 0 as B fragments
    h4_t zb[4];
    #pragma unroll
    for (int i = 0; i < 4; ++i)
        zb[i] = (h4_t){(_Float16)0, (_Float16)0, (_Float16)0, (_Float16)0};

    int sbuf = 0;
    for (int t = 0; t < T_; ++t) {
        // current buf's 12 loads are >= 48 vmem-ops old -> vmcnt(24) retires
        // them; the youngest 24 (recent stores + last stage) stay in flight.
        asm volatile("s_waitcnt vmcnt(24)" ::: "memory");

        f4 pmv[4], psv[4], evv[4];
        #pragma unroll
        for (int rt = 0; rt < 4; ++rt) {
            pmv[rt] = *reinterpret_cast<const f4*>(&stg[sbuf][rt][l * 4]);
            psv[rt] = *reinterpret_cast<const f4*>(&stg[sbuf][4 + rt][l * 4]);
            evv[rt] = *reinterpret_cast<const f4*>(&stg[sbuf][8 + rt][l * 4]);
        }
        // reads done before this buffer is overwritten below
        asm volatile("s_waitcnt lgkmcnt(0)" ::: "memory");

        if (t + 3 < T_) {
            const size_t row = ((size_t)(b0 + col) * T_ + (t + 3)) * 64 + 4 * g;
            #pragma unroll
            for (int rt = 0; rt < 4; ++rt) {
                stage16(pre_mu  + row + rt * 16, &stg[sbuf][rt][0]);
                stage16(pre_std + row + rt * 16, &stg[sbuf][4 + rt][0]);
                stage16(eps     + row + rt * 16, &stg[sbuf][8 + rt][0]);
            }
        }

        // D = W * z_{t-1} + pre   (C-init = pre fragments; 4-deep k chains)
        f4 am[4], as_[4];
        #pragma unroll
        for (int rt = 0; rt < 4; ++rt) { am[rt] = pmv[rt]; as_[rt] = psv[rt]; }
        #pragma unroll
        for (int kt = 0; kt < 4; ++kt) {
            #pragma unroll
            for (int rt = 0; rt < 4; ++rt) {
                am[rt]  = __builtin_amdgcn_mfma_f32_16x16x16f16(wm[rt][kt], zb[kt], am[rt],  0, 0, 0);
                as_[rt] = __builtin_amdgcn_mfma_f32_16x16x16f16(ws[rt][kt], zb[kt], as_[rt], 0, 0, 0);
            }
        }

        // epilogue: softplus, z, stores, and z -> f16 B-fragments for t+1
        const size_t orow = ((size_t)(b0 + col) * T_ + t) * 64 + 4 * g;
        #pragma unroll
        for (int rt = 0; rt < 4; ++rt) {
            const f4 mu4 = am[rt];
            const f4 sx4 = as_[rt];
            const f4 ev4 = evv[rt];
            f4 sd4, z4;
            h4_t zz;
            #pragma unroll
            for (int i = 0; i < 4; ++i) {
                const float sx = sx4[i];
                const float sp = (sx > 20.0f) ? sx : __logf(1.0f + __expf(sx));
                const float sd = sp + 1e-4f;
                sd4[i] = sd;
                const float zi = fmaf(ev4[i], sd, mu4[i]);
                z4[i]  = zi;
                zz[i]  = (_Float16)zi;
            }
            *reinterpret_cast<f4*>(&zo[orow + rt * 16])  = z4;
            *reinterpret_cast<f4*>(&muo[orow + rt * 16]) = mu4;
            *reinterpret_cast<f4*>(&sdo[orow + rt * 16]) = sd4;
            zb[rt] = zz;
        }

        sbuf = (sbuf == 2) ? 0 : sbuf + 1;
    }
}

extern "C" void kernel_launch(void* const* d_in, const int* in_sizes, int n_in,
                              void* d_out, int out_size, void* d_ws, size_t ws_size,
                              hipStream_t stream) {
    const float* input_q = (const float*)d_in[0];  // [B, T, H]
    const float* eps     = (const float*)d_in[1];  // [B, T, Z]
    const float* W_mu    = (const float*)d_in[2];  // [Z, H+Z]
    const float* b_mu    = (const float*)d_in[3];  // [Z]
    const float* W_std   = (const float*)d_in[4];  // [Z, H+Z]
    const float* b_std   = (const float*)d_in[5];  // [Z]
    float* out = (float*)d_out;

    float* pre_mu  = (float*)d_ws;                      // [M_, 64]
    float* pre_std = pre_mu + (size_t)M_ * Z_;          // [M_, 64]

    precompute_kernel<<<M_ / 64, 256, 0, stream>>>(
        input_q, W_mu, W_std, b_mu, b_std, pre_mu, pre_std);

    recurrent_kernel<<<B_ / 16, 64, 0, stream>>>(
        pre_mu, pre_std, eps, W_mu, W_std, out);
}

// Round 10
// 1260.798 us; speedup vs baseline: 1.1045x; 1.1045x over previous
//
#include <hip/hip_runtime.h>
#include <math.h>
#include <stdint.h>

#define B_ 128
#define T_ 1024
#define H_ 256
#define Z_ 64
#define M_ (B_ * T_)   // 131072 rows

typedef float     f4   __attribute__((ext_vector_type(4)));
typedef _Float16  h4_t __attribute__((ext_vector_type(4)));

// ---------------------------------------------------------------------------
// Kernel 1: precompute the non-recurrent part of both matmuls (unchanged).
// ---------------------------------------------------------------------------
__global__ __launch_bounds__(256) void precompute_kernel(
    const float* __restrict__ Hm,    // [M_, 256]
    const float* __restrict__ Wmu,   // [64, 320]
    const float* __restrict__ Wstd,  // [64, 320]
    const float* __restrict__ bmu,   // [64]
    const float* __restrict__ bstd,  // [64]
    float* __restrict__ pre_mu,      // [M_, 64]
    float* __restrict__ pre_std)     // [M_, 64]
{
    const int tid = threadIdx.x;
    const int ty = tid >> 4;
    const int tx = tid & 15;
    const int m0 = blockIdx.x * 64;

    __shared__ float Ash[64][17];
    __shared__ float Wm[64][17];
    __shared__ float Ws[64][17];

    float accm[4][4] = {};
    float accs[4][4] = {};

    const int lrow = tid >> 2;
    const int lk   = (tid & 3) * 4;

    for (int k0 = 0; k0 < 256; k0 += 16) {
        float4 av  = *reinterpret_cast<const float4*>(&Hm[(size_t)(m0 + lrow) * H_ + k0 + lk]);
        float4 wmv = *reinterpret_cast<const float4*>(&Wmu[(size_t)lrow * 320 + k0 + lk]);
        float4 wsv = *reinterpret_cast<const float4*>(&Wstd[(size_t)lrow * 320 + k0 + lk]);
        __syncthreads();
        Ash[lrow][lk + 0] = av.x;  Ash[lrow][lk + 1] = av.y;
        Ash[lrow][lk + 2] = av.z;  Ash[lrow][lk + 3] = av.w;
        Wm[lrow][lk + 0] = wmv.x;  Wm[lrow][lk + 1] = wmv.y;
        Wm[lrow][lk + 2] = wmv.z;  Wm[lrow][lk + 3] = wmv.w;
        Ws[lrow][lk + 0] = wsv.x;  Ws[lrow][lk + 1] = wsv.y;
        Ws[lrow][lk + 2] = wsv.z;  Ws[lrow][lk + 3] = wsv.w;
        __syncthreads();

        #pragma unroll
        for (int kk = 0; kk < 16; ++kk) {
            float a4[4], wm4[4], ws4[4];
            #pragma unroll
            for (int i = 0; i < 4; ++i) a4[i] = Ash[ty * 4 + i][kk];
            #pragma unroll
            for (int jj = 0; jj < 4; ++jj) wm4[jj] = Wm[tx * 4 + jj][kk];
            #pragma unroll
            for (int jj = 0; jj < 4; ++jj) ws4[jj] = Ws[tx * 4 + jj][kk];
            #pragma unroll
            for (int i = 0; i < 4; ++i)
                #pragma unroll
                for (int jj = 0; jj < 4; ++jj) {
                    accm[i][jj] += a4[i] * wm4[jj];
                    accs[i][jj] += a4[i] * ws4[jj];
                }
        }
    }

    float4 bm = *reinterpret_cast<const float4*>(&bmu[tx * 4]);
    float4 bs = *reinterpret_cast<const float4*>(&bstd[tx * 4]);
    #pragma unroll
    for (int i = 0; i < 4; ++i) {
        const size_t m = (size_t)(m0 + ty * 4 + i);
        float4 om, os;
        om.x = accm[i][0] + bm.x;  om.y = accm[i][1] + bm.y;
        om.z = accm[i][2] + bm.z;  om.w = accm[i][3] + bm.w;
        os.x = accs[i][0] + bs.x;  os.y = accs[i][1] + bs.y;
        os.z = accs[i][2] + bs.z;  os.w = accs[i][3] + bs.w;
        *reinterpret_cast<float4*>(&pre_mu[m * Z_ + tx * 4])  = om;
        *reinterpret_cast<float4*>(&pre_std[m * Z_ + tx * 4]) = os;
    }
}

// ---------------------------------------------------------------------------
// async 16B global -> LDS (wave-uniform LDS base; HW writes base + lane*16)
// ---------------------------------------------------------------------------
__device__ __forceinline__ void stage16(const float* g, float* lds_base) {
    __builtin_amdgcn_global_load_lds(
        (const __attribute__((address_space(1))) uint32_t*)(uintptr_t)g,
        (__attribute__((address_space(3))) uint32_t*)(uintptr_t)lds_base,
        16, 0, 0);
}

// ---------------------------------------------------------------------------
// Kernel 2: MFMA recurrence. One wave per 16 batch rows (8 blocks total).
//
// Layout identity (16x16x16 f16): D's (m,lane) mapping == B's (k,lane)
// mapping, so step t's z output feeds step t+1's B operand with only
// f32->f16 converts — the 64-way z broadcast costs zero cross-lane ops.
//
// R9 lesson: C++ reads of LDS written by global_load_lds make the compiler's
// waitcnt pass insert a conservative s_waitcnt vmcnt(0) in the loop (it
// can't track the ring's aliasing) -> every step drained the previous
// step's stores + stage loads = ~2200 cy/step of stall. Fix: do the LDS
// reads inside ONE asm volatile block (12x ds_read_b128 + lgkmcnt(0), no
// memory clobber) so the pass never sees an LDS data dependency; ordering
// vs the DMA is enforced by OUR counted waits only:
//   depth-4 ring, loop-top vmcnt(48) = leave last 2 iterations' (12 stage +
//   12 store) ops in flight, wait only for ops >= 3 iterations old.
//   NEVER vmcnt(0) in-loop (R1 lesson).
// ---------------------------------------------------------------------------
__global__ __launch_bounds__(64)
__attribute__((amdgpu_waves_per_eu(1, 1)))
void recurrent_kernel(
    const float* __restrict__ pre_mu,   // [M_, 64]
    const float* __restrict__ pre_std,  // [M_, 64]
    const float* __restrict__ eps,      // [B_, T_, 64]
    const float* __restrict__ Wmu,      // [64, 320]
    const float* __restrict__ Wstd,     // [64, 320]
    float* __restrict__ out)            // z | mu | std, each [B_, T_, 64]
{
    const int l   = threadIdx.x;
    const int col = l & 15;            // batch row within the 16-group
    const int g   = l >> 4;            // 0..3
    const int b0  = blockIdx.x * 16;

    // ---- A-fragments for both weight matrices: wm/ws[rt][kt], f16 ----
    h4_t wm[4][4], ws[4][4];
    #pragma unroll
    for (int rt = 0; rt < 4; ++rt) {
        #pragma unroll
        for (int kt = 0; kt < 4; ++kt) {
            const size_t off = (size_t)(rt * 16 + col) * 320 + 256 + kt * 16 + 4 * g;
            const f4 a = *reinterpret_cast<const f4*>(&Wmu[off]);
            const f4 s = *reinterpret_cast<const f4*>(&Wstd[off]);
            h4_t wa, wb;
            wa[0] = (_Float16)a[0]; wa[1] = (_Float16)a[1];
            wa[2] = (_Float16)a[2]; wa[3] = (_Float16)a[3];
            wb[0] = (_Float16)s[0]; wb[1] = (_Float16)s[1];
            wb[2] = (_Float16)s[2]; wb[3] = (_Float16)s[3];
            wm[rt][kt] = wa;
            ws[rt][kt] = wb;
        }
    }
    #pragma unroll
    for (int rt = 0; rt < 4; ++rt)
        #pragma unroll
        for (int kt = 0; kt < 4; ++kt) {
            asm volatile("" : "+v"(wm[rt][kt]));
            asm volatile("" : "+v"(ws[rt][kt]));
        }

    // LDS staging ring: 4 bufs x (4 pre_mu + 4 pre_std + 4 eps tiles) x 1KB
    __shared__ float stg[4][12][256];

    float* __restrict__ zo  = out;
    float* __restrict__ muo = out + (size_t)M_ * Z_;
    float* __restrict__ sdo = out + (size_t)2 * M_ * Z_;

    // prologue: stage t = 0..3 (48 vmem ops)
    #pragma unroll
    for (int s = 0; s < 4; ++s) {
        const size_t row = ((size_t)(b0 + col) * T_ + s) * 64 + 4 * g;
        #pragma unroll
        for (int rt = 0; rt < 4; ++rt) {
            stage16(pre_mu  + row + rt * 16, &stg[s][rt][0]);
            stage16(pre_std + row + rt * 16, &stg[s][4 + rt][0]);
            stage16(eps     + row + rt * 16, &stg[s][8 + rt][0]);
        }
    }
    // buf0's 12 loads are the oldest of 48 -> vmcnt(36) retires exactly them
    asm volatile("s_waitcnt vmcnt(36)");

    // z_{-1} = 0 as B fragments
    h4_t zb[4];
    #pragma unroll
    for (int i = 0; i < 4; ++i)
        zb[i] = (h4_t){(_Float16)0, (_Float16)0, (_Float16)0, (_Float16)0};

    int sbuf = 0;
    for (int t = 0; t < T_; ++t) {
        // leave last 2 iterations' 48 vmem ops in flight; everything older
        // (incl. this buf's stage, >= 3 iters / prologue ago) is retired.
        asm volatile("s_waitcnt vmcnt(48)");

        // LDS reads hidden from the compiler's waitcnt pass: one asm block,
        // wait INSIDE the block (no separate-wait hoist hazard).
        const unsigned a32 =
            (unsigned)(uintptr_t)&stg[sbuf][0][0] + 16u * (unsigned)l;
        f4 pm0, pm1, pm2, pm3, ps0, ps1, ps2, ps3, ev0, ev1, ev2, ev3;
        asm volatile(
            "ds_read_b128 %0, %12 offset:0\n\t"
            "ds_read_b128 %1, %12 offset:1024\n\t"
            "ds_read_b128 %2, %12 offset:2048\n\t"
            "ds_read_b128 %3, %12 offset:3072\n\t"
            "ds_read_b128 %4, %12 offset:4096\n\t"
            "ds_read_b128 %5, %12 offset:5120\n\t"
            "ds_read_b128 %6, %12 offset:6144\n\t"
            "ds_read_b128 %7, %12 offset:7168\n\t"
            "ds_read_b128 %8, %12 offset:8192\n\t"
            "ds_read_b128 %9, %12 offset:9216\n\t"
            "ds_read_b128 %10, %12 offset:10240\n\t"
            "ds_read_b128 %11, %12 offset:11264\n\t"
            "s_waitcnt lgkmcnt(0)"
            : "=&v"(pm0), "=&v"(pm1), "=&v"(pm2), "=&v"(pm3),
              "=&v"(ps0), "=&v"(ps1), "=&v"(ps2), "=&v"(ps3),
              "=&v"(ev0), "=&v"(ev1), "=&v"(ev2), "=&v"(ev3)
            : "v"(a32));
        __builtin_amdgcn_sched_barrier(0);

        // stage t+4 into this (now-consumed) buffer
        if (t + 4 < T_) {
            const size_t row = ((size_t)(b0 + col) * T_ + (t + 4)) * 64 + 4 * g;
            #pragma unroll
            for (int rt = 0; rt < 4; ++rt) {
                stage16(pre_mu  + row + rt * 16, &stg[sbuf][rt][0]);
                stage16(pre_std + row + rt * 16, &stg[sbuf][4 + rt][0]);
                stage16(eps     + row + rt * 16, &stg[sbuf][8 + rt][0]);
            }
        }

        const f4 pmv[4] = {pm0, pm1, pm2, pm3};
        const f4 psv[4] = {ps0, ps1, ps2, ps3};
        const f4 evv[4] = {ev0, ev1, ev2, ev3};

        // D = W * z_{t-1} + pre   (C-init = pre fragments; 4-deep k chains)
        f4 am[4], as_[4];
        #pragma unroll
        for (int rt = 0; rt < 4; ++rt) { am[rt] = pmv[rt]; as_[rt] = psv[rt]; }
        #pragma unroll
        for (int kt = 0; kt < 4; ++kt) {
            #pragma unroll
            for (int rt = 0; rt < 4; ++rt) {
                am[rt]  = __builtin_amdgcn_mfma_f32_16x16x16f16(wm[rt][kt], zb[kt], am[rt],  0, 0, 0);
                as_[rt] = __builtin_amdgcn_mfma_f32_16x16x16f16(ws[rt][kt], zb[kt], as_[rt], 0, 0, 0);
            }
        }

        // epilogue: softplus, z, stores, and z -> f16 B-fragments for t+1
        const size_t orow = ((size_t)(b0 + col) * T_ + t) * 64 + 4 * g;
        #pragma unroll
        for (int rt = 0; rt < 4; ++rt) {
            const f4 mu4 = am[rt];
            const f4 sx4 = as_[rt];
            const f4 ev4 = evv[rt];
            f4 sd4, z4;
            h4_t zz;
            #pragma unroll
            for (int i = 0; i < 4; ++i) {
                const float sx = sx4[i];
                const float sp = (sx > 20.0f) ? sx : __logf(1.0f + __expf(sx));
                const float sd = sp + 1e-4f;
                sd4[i] = sd;
                const float zi = fmaf(ev4[i], sd, mu4[i]);
                z4[i]  = zi;
                zz[i]  = (_Float16)zi;
            }
            *reinterpret_cast<f4*>(&zo[orow + rt * 16])  = z4;
            *reinterpret_cast<f4*>(&muo[orow + rt * 16]) = mu4;
            *reinterpret_cast<f4*>(&sdo[orow + rt * 16]) = sd4;
            zb[rt] = zz;
        }

        sbuf = (sbuf + 1) & 3;
    }
}

extern "C" void kernel_launch(void* const* d_in, const int* in_sizes, int n_in,
                              void* d_out, int out_size, void* d_ws, size_t ws_size,
                              hipStream_t stream) {
    const float* input_q = (const float*)d_in[0];  // [B, T, H]
    const float* eps     = (const float*)d_in[1];  // [B, T, Z]
    const float* W_mu    = (const float*)d_in[2];  // [Z, H+Z]
    const float* b_mu    = (const float*)d_in[3];  // [Z]
    const float* W_std   = (const float*)d_in[4];  // [Z, H+Z]
    const float* b_std   = (const float*)d_in[5];  // [Z]
    float* out = (float*)d_out;

    float* pre_mu  = (float*)d_ws;                      // [M_, 64]
    float* pre_std = pre_mu + (size_t)M_ * Z_;          // [M_, 64]

    precompute_kernel<<<M_ / 64, 256, 0, stream>>>(
        input_q, W_mu, W_std, b_mu, b_std, pre_mu, pre_std);

    recurrent_kernel<<<B_ / 16, 64, 0, stream>>>(
        pre_mu, pre_std, eps, W_mu, W_std, out);
}